// Round 14
// baseline (49.451 us; speedup 1.0000x reference)
//
#include <hip/hip_runtime.h>

#define HH 128
#define NN 64
#define LL 256
#define WP 280   // u16 pitch: 140 dwords = 12 mod 32 -> conflict-free b128 rows

typedef __attribute__((ext_vector_type(8))) short bf8;
typedef __attribute__((ext_vector_type(4))) float f32x4;

__device__ inline ushort f2bf(float f) {
    uint x = __float_as_uint(f);
    return (ushort)((x + 0x7fffu + ((x >> 16) & 1u)) >> 16);
}
__device__ inline uint cvt_pk_bf16(float lo, float hi) {
    uint r;
    asm volatile("v_cvt_pk_bf16_f32 %0, %1, %2" : "=v"(r) : "v"(lo), "v"(hi));
    return r;
}
#define MFMA(a,b,c) __builtin_amdgcn_mfma_f32_16x16x32_bf16((a),(b),(c),0,0,0)

// Tap generation. Output: parity-split pair tables per (s,h):
// arrg[(s*HH+h)*512 + j]       = rev[2j]   | rev[2j+1]<<16   (arrE)
// arrg[(s*HH+h)*512 + 256 + j] = rev[2j+1] | rev[2j+2]<<16   (arrO, rev[512]=0)
// rev[i] = kcat_s[h][511-i].
__global__ __launch_bounds__(512) void ssm_gen_fast(
    const float* __restrict__ A_re0, const float* __restrict__ A_im0,
    const float* __restrict__ C_re0, const float* __restrict__ C_im0,
    const float* __restrict__ log_dt0,
    const float* __restrict__ A_re1, const float* __restrict__ A_im1,
    const float* __restrict__ C_re1, const float* __restrict__ C_im1,
    const float* __restrict__ log_dt1,
    uint* __restrict__ arrg)
{
    __shared__ float4 par[128];
    __shared__ float  red[512];
    __shared__ ushort rev[512];

    int tid = threadIdx.x;
    int h   = blockIdx.x;
    int s   = blockIdx.y;

    if (tid < 128) {
        int n  = tid & 63;
        int ch = tid >> 6;
        const float* Ar = s ? A_re1 : A_re0;
        const float* Ai = s ? A_im1 : A_im0;
        const float* Cr = s ? C_re1 : C_re0;
        const float* Ci = s ? C_im1 : C_im0;
        const float* Ld = s ? log_dt1 : log_dt0;
        float dt = __expf(Ld[h]);
        float ar = Ar[h*NN + n], ai = Ai[h*NN + n];
        float cr = Cr[(ch*HH + h)*NN + n], ci = Ci[(ch*HH + h)*NN + n];
        float xr = dt * ar, xi = dt * ai;
        float phr = xi * 0.15915494f;
        float phf = phr - floorf(phr);
        float sn = __sinf(6.2831853f * phf);
        float cs = __cosf(6.2831853f * phf);
        float e  = __expf(xr);
        float er = e*cs - 1.f, ei = e*sn;
        float inv = 1.f / (ar*ar + ai*ai);
        float dr = (er*ar + ei*ai) * inv;
        float di = (ei*ar - er*ai) * inv;
        float Kr = 2.f*(cr*dr - ci*di);
        float Ki = 2.f*(cr*di + ci*dr);
        par[tid] = (float4){ xr, xi * 0.15915494f, Kr, Ki };
    }
    __syncthreads();

    {
        int l  = tid & 255;
        int ch = tid >> 8;
        float lf = (float)l;
#pragma unroll
        for (int nh = 0; nh < 2; ++nh) {
            const float4* pb = &par[ch*64 + nh*32];
            float acc = 0.f;
            for (int n = 0; n < 32; ++n) {
                float4 p = pb[n];
                float mag = __expf(p.x * lf);
                float ph  = p.y * lf;
                float phf = ph - floorf(ph);
                float ang = 6.2831853f * phf;
                acc += p.z * (mag * __cosf(ang)) - p.w * (mag * __sinf(ang));
            }
            if (nh == 0) red[tid] = acc;
            else {
                int ri = ch ? (256 + l) : (255 - l);
                rev[ri] = f2bf(red[tid] + acc);
            }
        }
    }
    __syncthreads();

    {
        int j  = tid & 255;
        uint lo, hi;
        if (tid < 256) { lo = rev[2*j];     hi = rev[2*j + 1]; }
        else           { lo = rev[2*j + 1]; hi = (j == 255) ? 0u : (uint)rev[2*j + 2]; }
        arrg[(s*HH + h)*512 + tid] = lo | (hi << 16);
    }
}

// Fused S4ND per (b, h, y-half), 512 threads / 8 waves, 2 blocks/CU.
// Rolling-window Toeplitz fragments: frag(kk,mi) = F(t), t = 2kk - mi.
__global__ __launch_bounds__(512, 4) void s4nd_v4(
    const float* __restrict__ u, const float* __restrict__ Dv,
    const uint* __restrict__ arrg, float* __restrict__ out)
{
    __shared__ ushort WT[128 * WP];       // 71680 B
    __shared__ uint   arr[2][512];        // 4096 B : [s][0..255]=arrE, [256..511]=arrO

    int tid = threadIdx.x;

    // XCD-pairing swizzle: both y-halves of a bh on the same XCD, adjacent.
    int j    = blockIdx.x;
    int xcd  = j & 7;
    int k    = j >> 3;
    int bh   = xcd * 32 + (k >> 1);
    int y0   = (k & 1) * 128;
    int h    = bh & (HH - 1);

    arr[0][tid] = arrg[h*512 + tid];
    arr[1][tid] = arrg[(HH + h)*512 + tid];
    __syncthreads();

    int lane = tid & 63;
    int w = tid >> 6;                 // 0..7
    int c = lane & 15, q = lane >> 4;
    int wm2 = (w >> 1) * 64, wn2 = (w & 1) * 64;

    // parity-table bases: c odd -> arrE (offset 0), c even -> arrO (offset 256)
    const uint* T1 = &arr[0][(c & 1) ? 0 : 256];
    const uint* T2 = &arr[1][(c & 1) ? 0 : 256];
    int jb2 = (255 - y0  - c + 8*q) >> 1;   // ph1: j = jb2 + 8t
    int jb1 = (255 - wm2 - c + 8*q) >> 1;   // ph2: j = jb1 + 8t

    f32x4 acc[16];
#pragma unroll
    for (int i = 0; i < 16; ++i) acc[i] = (f32x4){0.f,0.f,0.f,0.f};

    const float* ub = u + (size_t)bh * LL * LL;
    const float* rp0 = ub + (size_t)(w*32 +  0 + c) * LL;
    const float* rp1 = ub + (size_t)(w*32 + 16 + c) * LL;

    // ---- phase 1: y-conv, rolling 8-frag window, no barriers ----
    bf8 win[8];
#pragma unroll
    for (int t = -7; t <= 0; ++t) {
        int jj = jb2 + 8*t;
        uint* pw = (uint*)&win[t & 7];
        pw[0] = T2[jj]; pw[1] = T2[jj+1]; pw[2] = T2[jj+2]; pw[3] = T2[jj+3];
    }
#pragma unroll
    for (int kk = 0; kk < 8; ++kk) {
        if (kk) {
#pragma unroll
            for (int t = 2*kk - 1; t <= 2*kk; ++t) {
                int jj = jb2 + 8*t;
                uint* pw = (uint*)&win[t & 7];
                pw[0] = T2[jj]; pw[1] = T2[jj+1]; pw[2] = T2[jj+2]; pw[3] = T2[jj+3];
            }
        }
        int yb = kk*32 + 8*q;
        float4 A0 = *(const float4*)(rp0 + yb);
        float4 A1 = *(const float4*)(rp0 + yb + 4);
        float4 A2 = *(const float4*)(rp1 + yb);
        float4 A3 = *(const float4*)(rp1 + yb + 4);
        bf8 b0, b1;
        uint* p0 = (uint*)&b0; uint* p1 = (uint*)&b1;
        p0[0] = cvt_pk_bf16(A0.x, A0.y); p0[1] = cvt_pk_bf16(A0.z, A0.w);
        p0[2] = cvt_pk_bf16(A1.x, A1.y); p0[3] = cvt_pk_bf16(A1.z, A1.w);
        p1[0] = cvt_pk_bf16(A2.x, A2.y); p1[1] = cvt_pk_bf16(A2.z, A2.w);
        p1[2] = cvt_pk_bf16(A3.x, A3.y); p1[3] = cvt_pk_bf16(A3.z, A3.w);
        __builtin_amdgcn_s_setprio(1);
#pragma unroll
        for (int mi = 0; mi < 8; ++mi) {
            bf8 a = win[(2*kk - mi) & 7];
            acc[mi*2 + 0] = MFMA(a, b0, acc[mi*2 + 0]);
            acc[mi*2 + 1] = MFMA(a, b1, acc[mi*2 + 1]);
        }
        __builtin_amdgcn_s_setprio(0);
    }

    // ---- acc -> WT ----
#pragma unroll
    for (int mi = 0; mi < 8; ++mi)
#pragma unroll
        for (int ni = 0; ni < 2; ++ni)
#pragma unroll
            for (int r = 0; r < 4; ++r) {
                int row = 16*mi + 4*q + r;
                int col = w*32 + 16*ni + c;
                WT[row*WP + col] = f2bf(acc[mi*2 + ni][r]);
                acc[mi*2 + ni][r] = 0.f;
            }
    __syncthreads();

    // ---- phase 2: x-conv, merged 64-col strip, rolling 4-frag window ----
    bf8 win2[4];
#pragma unroll
    for (int t = -3; t <= 0; ++t) {
        int jj = jb1 + 8*t;
        uint* pw = (uint*)&win2[t & 3];
        pw[0] = T1[jj]; pw[1] = T1[jj+1]; pw[2] = T1[jj+2]; pw[3] = T1[jj+3];
    }
#pragma unroll
    for (int kk = 0; kk < 8; ++kk) {
        if (kk) {
#pragma unroll
            for (int t = 2*kk - 1; t <= 2*kk; ++t) {
                int jj = jb1 + 8*t;
                uint* pw = (uint*)&win2[t & 3];
                pw[0] = T1[jj]; pw[1] = T1[jj+1]; pw[2] = T1[jj+2]; pw[3] = T1[jj+3];
            }
        }
        int xb = kk*32;
        bf8 b[4];
#pragma unroll
        for (int ni = 0; ni < 4; ++ni)
            b[ni] = *(const bf8*)&WT[(wn2 + 16*ni + c)*WP + xb + 8*q];
        __builtin_amdgcn_s_setprio(1);
#pragma unroll
        for (int mi = 0; mi < 4; ++mi) {
            bf8 a = win2[(2*kk - mi) & 3];
#pragma unroll
            for (int ni = 0; ni < 4; ++ni)
                acc[mi*4 + ni] = MFMA(a, b[ni], acc[mi*4 + ni]);
        }
        __builtin_amdgcn_s_setprio(0);
    }

    // ---- epilogue: Y + D*u -> global ----
    float dh = Dv[h];
    float* yb_ = out + (size_t)bh * LL * LL;
#pragma unroll
    for (int mi = 0; mi < 4; ++mi)
#pragma unroll
        for (int ni = 0; ni < 4; ++ni)
#pragma unroll
            for (int r = 0; r < 4; ++r) {
                int row = wm2 + 16*mi + 4*q + r;
                int col = y0 + wn2 + 16*ni + c;
                size_t o = (size_t)row * LL + col;
                yb_[o] = acc[mi*4 + ni][r] + dh * ub[o];
            }
}

extern "C" void kernel_launch(void* const* d_in, const int* in_sizes, int n_in,
                              void* d_out, int out_size, void* d_ws, size_t ws_size,
                              hipStream_t stream)
{
    const float* u       = (const float*)d_in[0];
    const float* D       = (const float*)d_in[1];
    const float* A_re0   = (const float*)d_in[2];
    const float* A_im0   = (const float*)d_in[3];
    const float* C_re0   = (const float*)d_in[4];
    const float* C_im0   = (const float*)d_in[5];
    const float* log_dt0 = (const float*)d_in[6];
    const float* A_re1   = (const float*)d_in[7];
    const float* A_im1   = (const float*)d_in[8];
    const float* C_re1   = (const float*)d_in[9];
    const float* C_im1   = (const float*)d_in[10];
    const float* log_dt1 = (const float*)d_in[11];
    float* out = (float*)d_out;

    uint* arrg = (uint*)d_ws;   // 2*128*512 u32 = 512 KB

    ssm_gen_fast<<<dim3(HH, 2), 512, 0, stream>>>(
        A_re0, A_im0, C_re0, C_im0, log_dt0,
        A_re1, A_im1, C_re1, C_im1, log_dt1, arrg);
    s4nd_v4<<<512, 512, 0, stream>>>(u, D, arrg, out);
}